// Round 18
// baseline (73.404 us; speedup 1.0000x reference)
//
#include <hip/hip_runtime.h>
#include <hip/hip_bf16.h>

#define B_ 8
#define S_ 2048
#define D_ 256
#define U_ 128
#define BS_ (B_*S_)

using bf16 = __hip_bfloat16;
typedef __attribute__((ext_vector_type(8))) __bf16 bf8v;      // MFMA A/B frag (4 VGPR)
typedef __attribute__((ext_vector_type(4))) float f4v;        // 16x16 C/D frag
typedef __attribute__((ext_vector_type(16))) float f16v;      // 32x32 C/D frag
typedef __attribute__((ext_vector_type(4))) float float4v;
typedef __attribute__((ext_vector_type(4))) unsigned short us4;
typedef __attribute__((ext_vector_type(8))) unsigned short us8;
typedef __attribute__((ext_vector_type(4))) unsigned int u4v;
typedef __attribute__((ext_vector_type(2))) unsigned int u2v;

#define MFMA16(a,b,c) __builtin_amdgcn_mfma_f32_16x16x32_bf16((a),(b),(c),0,0,0)
#define MFMA32(a,b,c) __builtin_amdgcn_mfma_f32_32x32x16_bf16((a),(b),(c),0,0,0)

#if __has_builtin(__builtin_amdgcn_exp2f)
#define EXP2(x) __builtin_amdgcn_exp2f(x)
#else
#define EXP2(x) exp2f(x)
#endif

__device__ __forceinline__ unsigned short f2bits(float f){
  return __builtin_bit_cast(unsigned short, __float2bfloat16(f));
}
__device__ __forceinline__ float b2f(unsigned short u){
  return __builtin_bit_cast(float, ((unsigned)u) << 16);
}

// permlane32_swap (SSA builtin -> no register-aliasing hazard)
__device__ __forceinline__ void plswap(unsigned &a, unsigned &b){
#if __has_builtin(__builtin_amdgcn_permlane32_swap)
  u2v r = __builtin_amdgcn_permlane32_swap(a, b, 0, 0);
  a = r[0]; b = r[1];
#else
  unsigned as = (unsigned)__shfl_xor((int)a, 32);
  unsigned bs = (unsigned)__shfl_xor((int)b, 32);
  bool hi = (threadIdx.x & 32) != 0;
  unsigned na = hi ? bs : a;
  unsigned nb = hi ? b  : as;
  a = na; b = nb;
#endif
}
__device__ __forceinline__ float cross_max(float x){
  unsigned a = __builtin_bit_cast(unsigned, x), b = a;
  plswap(a, b);
  return fmaxf(__builtin_bit_cast(float, a), __builtin_bit_cast(float, b));
}
__device__ __forceinline__ float cross_sum(float x){
  unsigned a = __builtin_bit_cast(unsigned, x), b = a;
  plswap(a, b);
  return __builtin_bit_cast(float, a) + __builtin_bit_cast(float, b);
}

// async global->LDS, 16B per lane; LDS dest = wave-uniform base + lane*16
__device__ __forceinline__ void gload16(const void* g, void* l){
  __builtin_amdgcn_global_load_lds(
    (const __attribute__((address_space(1))) char*)(unsigned long long)g,
    (__attribute__((address_space(3))) char*)(unsigned int)(unsigned long long)l,
    16, 0, 0);
}

// ---------------- prep: weights -> MFMA FRAGMENT order ----------------
__global__ __launch_bounds__(256) void prep_w_kernel(const float* __restrict__ Wq,
                                                     const float* __restrict__ Wk,
                                                     const float* __restrict__ Wv,
                                                     const float* __restrict__ Wo,
                                                     bf16* __restrict__ Wqf,
                                                     bf16* __restrict__ Wkf,
                                                     bf16* __restrict__ Wvf,
                                                     bf16* __restrict__ Wof){
  int t = blockIdx.x*256 + threadIdx.x;   // 16384 threads (64 blocks)
  int which = t >> 12;
  int c = t & 4095;
  int lane = c & 63;
  int lq = lane & 15, g = lane >> 4;
  us8 v;
  if (which < 3){
    int nt = c >> 9;            // 0..7
    int ks = (c >> 6) & 7;      // 0..7
    const float* src = (which==0)?Wq:((which==1)?Wk:Wv);
    bf16* dst = (which==0)?Wqf:((which==1)?Wkf:Wvf);
    #pragma unroll
    for (int j=0;j<8;j++) v[j] = f2bits(src[(size_t)(ks*32 + g*8 + j)*U_ + nt*16 + lq]);
    *reinterpret_cast<us8*>(dst + (size_t)c*8) = v;
  } else {
    int nt = c >> 8;            // 0..15
    int ks = (c >> 6) & 3;      // 0..3
    #pragma unroll
    for (int j=0;j<8;j++) v[j] = f2bits(Wo[(size_t)(ks*32 + g*8 + j)*D_ + nt*16 + lq]);
    *reinterpret_cast<us8*>(Wof + (size_t)c*8) = v;
  }
}

// ---------------- QKV projection: coalesced X staging + frag-order weights (r16) ----------------
__global__ __launch_bounds__(256) void qkv_kernel(const float* __restrict__ X,
                                                  const bf16* __restrict__ Wqf,
                                                  const bf16* __restrict__ Wkf,
                                                  const bf16* __restrict__ Wvf,
                                                  bf16* __restrict__ Q,
                                                  bf16* __restrict__ K,
                                                  bf16* __restrict__ Vt){
  __shared__ unsigned short Xls[32][264];   // pad 264: 528B rows

  const int tid  = threadIdx.x;
  const int w    = tid >> 6;
  const int lane = tid & 63;
  const int lq   = lane & 15;
  const int g    = lane >> 4;
  const int m0   = blockIdx.x*32;
  const int n0   = w*32;

  #pragma unroll
  for (int p=0; p<8; p++){
    int row = p*4 + (tid>>6);
    int col = (tid & 63)*4;
    float4v x = *reinterpret_cast<const float4v*>(X + (size_t)(m0+row)*D_ + col);
    us4 v;
    #pragma unroll
    for (int j=0;j<4;j++) v[j] = f2bits(x[j]);
    *reinterpret_cast<us4*>(&Xls[row][col]) = v;
  }
  __syncthreads();

  bf8v af[2][8];
  #pragma unroll
  for (int rt=0; rt<2; rt++)
    #pragma unroll
    for (int ks=0; ks<8; ks++)
      af[rt][ks] = *reinterpret_cast<const bf8v*>(&Xls[rt*16+lq][ks*32 + g*8]);

  #pragma unroll
  for (int which=0; which<3; which++){
    const bf16* Wf = (which==0) ? Wqf : ((which==1) ? Wkf : Wvf);
    f4v acc[2][2];
    #pragma unroll
    for (int rt=0;rt<2;rt++)
      #pragma unroll
      for (int ct=0;ct<2;ct++) acc[rt][ct] = (f4v){0.f,0.f,0.f,0.f};

    #pragma unroll
    for (int ks=0; ks<8; ks++){
      #pragma unroll
      for (int ct=0; ct<2; ct++){
        int nt = (n0>>4) + ct;
        bf8v b = *reinterpret_cast<const bf8v*>(Wf + ((size_t)((nt*8 + ks)*64 + lane) << 3));
        acc[0][ct] = MFMA16(af[0][ks], b, acc[0][ct]);
        acc[1][ct] = MFMA16(af[1][ks], b, acc[1][ct]);
      }
    }

    if (which==0){
      const float qscale = 0.12751745562008530f;      // log2(e)/sqrt(U)
      #pragma unroll
      for (int rt=0;rt<2;rt++)
        #pragma unroll
        for (int ct=0;ct<2;ct++)
          #pragma unroll
          for (int r=0;r<4;r++)
            Q[(size_t)(m0+rt*16+g*4+r)*U_ + n0+ct*16+lq] = __float2bfloat16(acc[rt][ct][r]*qscale);
    } else if (which==1){
      #pragma unroll
      for (int rt=0;rt<2;rt++)
        #pragma unroll
        for (int ct=0;ct<2;ct++)
          #pragma unroll
          for (int r=0;r<4;r++)
            K[(size_t)(m0+rt*16+g*4+r)*U_ + n0+ct*16+lq] = __float2bfloat16(acc[rt][ct][r]);
    } else {
      #pragma unroll
      for (int rt=0;rt<2;rt++)
        #pragma unroll
        for (int ct=0;ct<2;ct++)
          #pragma unroll
          for (int r=0;r<4;r++){
            int m = m0 + rt*16 + g*4 + r;
            int bb = m >> 11;              // /S_
            int ss = m & (S_-1);
            Vt[((size_t)bb*U_ + n0+ct*16+lq)*S_ + ss] = __float2bfloat16(acc[rt][ct][r]);
          }
    }
  }
}

// ---------------- flash attention: 4 independent QK^T MFMA chains ----------------
// r16 structure + split accumulators (stA0/stA1/stB0/stB1) to halve chain latency.
__global__ __launch_bounds__(256) void flash_kernel(const bf16* __restrict__ Q,
                                                    const bf16* __restrict__ K,
                                                    const bf16* __restrict__ Vt,
                                                    bf16* __restrict__ Opart,
                                                    float* __restrict__ Mst,
                                                    float* __restrict__ Lst,
                                                    int nsplit){
  __shared__ bf16 Kls[2][64*128];      // 2 x 16KB
  __shared__ bf16 Vls[2][128*64];      // 2 x 16KB

  const int n    = blockIdx.x;
  const int b    = n & 7;
  const int m    = n >> 3;
  const int s    = m % nsplit;
  const int qt   = m / nsplit;
  const int w    = threadIdx.x >> 6;
  const int lane = threadIdx.x & 63;
  const int l5   = lane & 31;
  const int hi   = lane >> 5;
  const int q0   = qt*128 + w*32;

  const int NT = S_/64;                // 32 big tiles
  const int t0 = (s*NT)/nsplit;
  const int t1 = ((s+1)*NT)/nsplit;

  const bf16* Qp = Q + (size_t)(b*S_ + q0 + l5)*U_ + hi*8;
  bf8v qf[8];
  #pragma unroll
  for (int uc=0; uc<8; uc++) qf[uc] = *reinterpret_cast<const bf8v*>(Qp + uc*16);

  f16v o[4];
  #pragma unroll
  for (int uc=0; uc<4; uc++)
    #pragma unroll
    for (int r=0; r<16; r++) o[uc][r] = 0.f;

  float mrow = -1e30f, lrow = 0.f;

  const bf16* Kbase = K  + (size_t)b*S_*U_;
  const bf16* Vtb   = Vt + (size_t)b*U_*S_;     // row u, stride S_

  auto stageK = [&](int buf, int t){
    const int r0 = w*16;
    #pragma unroll
    for (int c=0; c<4; c++){
      int row  = r0 + c*4 + (lane>>4);
      int soff = ((lane&15)<<4) ^ ((row&7)<<4);
      const char* src = (const char*)(Kbase + (size_t)(t*64 + row)*U_) + soff;
      gload16(src, (void*)&Kls[buf][(r0 + c*4)*128]);
    }
  };
  auto stageV = [&](int buf, int t){
    const int r0 = w*32;
    #pragma unroll
    for (int c=0; c<4; c++){
      int u    = r0 + c*8 + (lane>>3);
      int soff = ((lane&7)<<4) ^ ((u&7)<<4);
      const char* src = (const char*)(Vtb + (size_t)u*S_ + t*64) + soff;
      gload16(src, (void*)&Vls[buf][(r0 + c*8)*64]);
    }
  };

  // softmax + P-pack + PV for one 32-k subtile (two half-accumulators, summed here)
  auto process = [&](f16v &sa, f16v &sb, const char* vb0, int sub){
    float p[16];
    #pragma unroll
    for (int r=0;r<16;r++) p[r] = sa[r] + sb[r];

    float a0 = fmaxf(p[0],p[1]),  a1 = fmaxf(p[2],p[3]);
    float a2 = fmaxf(p[4],p[5]),  a3 = fmaxf(p[6],p[7]);
    float a4 = fmaxf(p[8],p[9]),  a5 = fmaxf(p[10],p[11]);
    float a6 = fmaxf(p[12],p[13]),a7 = fmaxf(p[14],p[15]);
    float b0 = fmaxf(a0,a1), b1 = fmaxf(a2,a3), b2 = fmaxf(a4,a5), b3 = fmaxf(a6,a7);
    float tm = fmaxf(fmaxf(b0,b1), fmaxf(b2,b3));
    tm = cross_max(tm);

    if (!__all(tm <= mrow + 11.54f)){        // defer-max (8 nats in log2)
      float mn    = fmaxf(mrow, tm);
      float alpha = EXP2(mrow - mn);
      lrow *= alpha;
      #pragma unroll
      for (int uc=0;uc<4;uc++)
        #pragma unroll
        for (int r=0;r<16;r++) o[uc][r] *= alpha;
      mrow = mn;
    }

    #pragma unroll
    for (int r=0;r<16;r++) p[r] = EXP2(p[r]-mrow);
    float s0s = (p[0]+p[1]) + (p[2]+p[3]);
    float s1s = (p[4]+p[5]) + (p[6]+p[7]);
    float s2s = (p[8]+p[9]) + (p[10]+p[11]);
    float s3s = (p[12]+p[13]) + (p[14]+p[15]);
    lrow += cross_sum((s0s+s1s) + (s2s+s3s));

    unsigned c0 = (unsigned)f2bits(p[0])  | ((unsigned)f2bits(p[1])<<16);
    unsigned c1 = (unsigned)f2bits(p[2])  | ((unsigned)f2bits(p[3])<<16);
    unsigned c2 = (unsigned)f2bits(p[4])  | ((unsigned)f2bits(p[5])<<16);
    unsigned c3 = (unsigned)f2bits(p[6])  | ((unsigned)f2bits(p[7])<<16);
    unsigned c4 = (unsigned)f2bits(p[8])  | ((unsigned)f2bits(p[9])<<16);
    unsigned c5 = (unsigned)f2bits(p[10]) | ((unsigned)f2bits(p[11])<<16);
    unsigned c6 = (unsigned)f2bits(p[12]) | ((unsigned)f2bits(p[13])<<16);
    unsigned c7 = (unsigned)f2bits(p[14]) | ((unsigned)f2bits(p[15])<<16);
    plswap(c0, c2);
    plswap(c1, c3);
    plswap(c4, c6);
    plswap(c5, c7);
    u4v w0v = {c0, c1, c2, c3};
    u4v w1v = {c4, c5, c6, c7};
    bf8v pa0 = __builtin_bit_cast(bf8v, w0v);   // P[q=l5][k = hi*8+j]
    bf8v pa1 = __builtin_bit_cast(bf8v, w1v);   // P[q=l5][k = 16+hi*8+j]

    __builtin_amdgcn_s_setprio(1);
    #pragma unroll
    for (int uc=0; uc<4; uc++){
      const char* vrow = vb0 + (uc*32 + l5)*128;
      bf8v v0 = *reinterpret_cast<const bf8v*>(vrow + ((sub*64      + hi*16) ^ ((l5&7)<<4)));
      bf8v v1 = *reinterpret_cast<const bf8v*>(vrow + ((sub*64 + 32 + hi*16) ^ ((l5&7)<<4)));
      o[uc] = MFMA32(v0, pa0, o[uc]);
      o[uc] = MFMA32(v1, pa1, o[uc]);
    }
    __builtin_amdgcn_s_setprio(0);
  };

  stageK(0, t0); stageV(0, t0);
  int cur = 0;
  for (int tt=t0; tt<t1; ++tt){
    int tn = (tt+1 < NT) ? (tt+1) : (NT-1);
    stageK(cur^1, tn); stageV(cur^1, tn);              // 8 vmem in flight for t+1
    asm volatile("s_waitcnt vmcnt(8)" ::: "memory");   // tile tt fully staged
    __builtin_amdgcn_s_barrier();
    unsigned bufoff = (unsigned)cur * 16384u;          // launder: pin LDS reads after barrier
    asm volatile("" : "+v"(bufoff) : : "memory");
    const char* kb0 = (const char*)&Kls[0][0] + bufoff;
    const char* vb0 = (const char*)&Vls[0][0] + bufoff;

    // ---- QK^T for BOTH subtiles up front: 4 INDEPENDENT MFMA chains of 4 ----
    f16v stA0, stA1, stB0, stB1;
    #pragma unroll
    for (int r=0;r<16;r++){ stA0[r]=0.f; stA1[r]=0.f; stB0[r]=0.f; stB1[r]=0.f; }
    __builtin_amdgcn_s_setprio(1);
    #pragma unroll
    for (int uc=0; uc<4; uc++){
      bf8v ka = *reinterpret_cast<const bf8v*>(kb0 + l5*256 + ((uc*64      + hi*16) ^ ((l5&7)<<4)));
      bf8v kc = *reinterpret_cast<const bf8v*>(kb0 + l5*256 + ((uc*64 + 32 + hi*16) ^ ((l5&7)<<4)));
      stA0 = MFMA32(ka, qf[2*uc],   stA0);
      stA1 = MFMA32(kc, qf[2*uc+1], stA1);
    }
    #pragma unroll
    for (int uc=0; uc<4; uc++){
      bf8v ka = *reinterpret_cast<const bf8v*>(kb0 + 8192 + l5*256 + ((uc*64      + hi*16) ^ ((l5&7)<<4)));
      bf8v kc = *reinterpret_cast<const bf8v*>(kb0 + 8192 + l5*256 + ((uc*64 + 32 + hi*16) ^ ((l5&7)<<4)));
      stB0 = MFMA32(ka, qf[2*uc],   stB0);
      stB1 = MFMA32(kc, qf[2*uc+1], stB1);
    }
    __builtin_amdgcn_s_setprio(0);

    process(stA0, stA1, vb0, 0);
    process(stB0, stB1, vb0, 1);

    asm volatile("" ::: "memory");
    __builtin_amdgcn_s_barrier();    // all waves done reading buffers before restage
    cur ^= 1;
  }

  // ---- epilogue: per-wave (q-rows disjoint) normalized partial + stats ----
  const size_t rowg = (size_t)(b*S_ + q0 + l5);
  if (hi==0){
    Mst[(size_t)s*BS_ + rowg] = mrow;
    Lst[(size_t)s*BS_ + rowg] = lrow;
  }
  float inv = 1.0f / lrow;
  bf16* Op = Opart + (size_t)s*BS_*U_ + rowg*U_;
  #pragma unroll
  for (int uc=0; uc<4; uc++){
    #pragma unroll
    for (int g2=0; g2<4; g2++){
      us4 outv;
      #pragma unroll
      for (int j=0;j<4;j++) outv[j] = f2bits(o[uc][g2*4+j]*inv);
      *reinterpret_cast<us4*>(Op + uc*32 + g2*8 + hi*4) = outv;
    }
  }
}

// ---------------- output projection + residual, combine fused + LDS-staged A + frag weights (r16) ----------------
template<int NS>
__global__ __launch_bounds__(256) void oproj_kernel(const bf16* __restrict__ Opart,
                                                    const float* __restrict__ Mst,
                                                    const float* __restrict__ Lst,
                                                    const bf16* __restrict__ Wof,
                                                    const float* __restrict__ X,
                                                    const float* __restrict__ bo,
                                                    float* __restrict__ Y){
  __shared__ unsigned short Als[64][136];

  const int tid  = threadIdx.x;
  const int w    = tid >> 6;
  const int lane = tid & 63;
  const int lq   = lane & 15;
  const int g    = lane >> 4;
  const int m0   = blockIdx.x*64;
  const int n0   = blockIdx.y*128;

  const unsigned short* Ou = reinterpret_cast<const unsigned short*>(Opart);
  #pragma unroll
  for (int p=0; p<4; p++){
    int rl  = p*16 + (tid>>4);
    int c8  = (tid & 15)*8;
    int row = m0 + rl;
    float cw[NS];
    float M = -1e30f;
    #pragma unroll
    for (int s=0;s<NS;s++){ cw[s] = Mst[(size_t)s*BS_ + row]; M = fmaxf(M, cw[s]); }
    float L = 0.f;
    #pragma unroll
    for (int s=0;s<NS;s++){ cw[s] = Lst[(size_t)s*BS_ + row]*EXP2(cw[s]-M); L += cw[s]; }
    float inv = 1.0f / L;
    float av[8];
    #pragma unroll
    for (int j=0;j<8;j++) av[j] = 0.f;
    #pragma unroll
    for (int s=0;s<NS;s++){
      us8 pp = *reinterpret_cast<const us8*>(Ou + (size_t)s*BS_*U_ + (size_t)row*U_ + c8);
      #pragma unroll
      for (int j=0;j<8;j++) av[j] += cw[s]*b2f(pp[j]);
    }
    us8 aw;
    #pragma unroll
    for (int j=0;j<8;j++) aw[j] = f2bits(av[j]*inv);
    *reinterpret_cast<us8*>(&Als[rl][c8]) = aw;
  }
  __syncthreads();

  f4v acc[8];
  #pragma unroll
  for (int i=0;i<8;i++) acc[i] = (f4v){0.f,0.f,0.f,0.f};

  #pragma unroll
  for (int ks=0; ks<4; ks++){
    bf8v a = *reinterpret_cast<const bf8v*>(&Als[w*16+lq][ks*32 + g*8]);
    #pragma unroll
    for (int nc=0;nc<8;nc++){
      int nt = (n0>>4) + nc;
      bf8v bb = *reinterpret_cast<const bf8v*>(Wof + ((size_t)((nt*4 + ks)*64 + lane) << 3));
      acc[nc] = MFMA16(a, bb, acc[nc]);
    }
  }

  #pragma unroll
  for (int nc=0;nc<8;nc++){
    int col = n0 + nc*16 + lq;
    float bias = bo[col];
    #pragma unroll
    for (int r=0;r<4;r++){
      int orow = m0 + w*16 + g*4 + r;
      Y[(size_t)orow*D_ + col] = acc[nc][r] + bias + X[(size_t)orow*D_ + col];
    }
  }
}

extern "C" void kernel_launch(void* const* d_in, const int* in_sizes, int n_in,
                              void* d_out, int out_size, void* d_ws, size_t ws_size,
                              hipStream_t stream) {
  (void)in_sizes; (void)n_in; (void)out_size;
  const float* X  = (const float*)d_in[0];
  const float* Wq = (const float*)d_in[1];
  const float* Wk = (const float*)d_in[2];
  const float* Wv = (const float*)d_in[3];
  const float* Wo = (const float*)d_in[4];
  const float* bo = (const float*)d_in[5];
  float* Y = (float*)d_out;

  const size_t MB = 1u<<20;
  int nsplit = (ws_size >= 30408704u) ? 4 : 2;   // ns=4 footprint ~29.1MB

  char* ws = (char*)d_ws;
  bf16* Opart = (bf16*)ws;
  size_t off = (size_t)nsplit*4*MB;
  bf16* Qb  = (bf16*)(ws + off); off += 4*MB;
  bf16* Kb  = (bf16*)(ws + off); off += 4*MB;
  bf16* Vtb = (bf16*)(ws + off); off += 4*MB;
  bf16* Wqf = (bf16*)(ws + off); off += 65536;
  bf16* Wkf = (bf16*)(ws + off); off += 65536;
  bf16* Wvf = (bf16*)(ws + off); off += 65536;
  bf16* Wof = (bf16*)(ws + off); off += 65536;
  float* Mst = (float*)(ws + off); off += (size_t)nsplit*BS_*4;
  float* Lst = (float*)(ws + off);

  prep_w_kernel<<<dim3(64), dim3(256), 0, stream>>>(Wq, Wk, Wv, Wo, Wqf, Wkf, Wvf, Wof);
  qkv_kernel<<<dim3(BS_/32), dim3(256), 0, stream>>>(X, Wqf, Wkf, Wvf, Qb, Kb, Vtb);
  flash_kernel<<<dim3(16*nsplit*8), dim3(256), 0, stream>>>(Qb, Kb, Vtb, Opart, Mst, Lst, nsplit);
  if (nsplit == 4){
    oproj_kernel<4><<<dim3(BS_/64, 2), dim3(256), 0, stream>>>(Opart, Mst, Lst, Wof, X, bo, Y);
  } else {
    oproj_kernel<2><<<dim3(BS_/64, 2), dim3(256), 0, stream>>>(Opart, Mst, Lst, Wof, X, bo, Y);
  }
}

// Round 19
// 69.006 us; speedup vs baseline: 1.0637x; 1.0637x over previous
//
#include <hip/hip_runtime.h>
#include <hip/hip_bf16.h>

#define B_ 8
#define S_ 2048
#define D_ 256
#define U_ 128
#define BS_ (B_*S_)

using bf16 = __hip_bfloat16;
typedef __attribute__((ext_vector_type(8))) __bf16 bf8v;      // MFMA A/B frag (4 VGPR)
typedef __attribute__((ext_vector_type(4))) float f4v;        // 16x16 C/D frag
typedef __attribute__((ext_vector_type(16))) float f16v;      // 32x32 C/D frag
typedef __attribute__((ext_vector_type(4))) float float4v;
typedef __attribute__((ext_vector_type(4))) unsigned short us4;
typedef __attribute__((ext_vector_type(8))) unsigned short us8;
typedef __attribute__((ext_vector_type(4))) unsigned int u4v;
typedef __attribute__((ext_vector_type(2))) unsigned int u2v;

#define MFMA16(a,b,c) __builtin_amdgcn_mfma_f32_16x16x32_bf16((a),(b),(c),0,0,0)
#define MFMA32(a,b,c) __builtin_amdgcn_mfma_f32_32x32x16_bf16((a),(b),(c),0,0,0)

#if __has_builtin(__builtin_amdgcn_exp2f)
#define EXP2(x) __builtin_amdgcn_exp2f(x)
#else
#define EXP2(x) exp2f(x)
#endif

__device__ __forceinline__ unsigned short f2bits(float f){
  return __builtin_bit_cast(unsigned short, __float2bfloat16(f));
}
__device__ __forceinline__ float b2f(unsigned short u){
  return __builtin_bit_cast(float, ((unsigned)u) << 16);
}

// permlane32_swap (SSA builtin -> no register-aliasing hazard)
__device__ __forceinline__ void plswap(unsigned &a, unsigned &b){
#if __has_builtin(__builtin_amdgcn_permlane32_swap)
  u2v r = __builtin_amdgcn_permlane32_swap(a, b, 0, 0);
  a = r[0]; b = r[1];
#else
  unsigned as = (unsigned)__shfl_xor((int)a, 32);
  unsigned bs = (unsigned)__shfl_xor((int)b, 32);
  bool hi = (threadIdx.x & 32) != 0;
  unsigned na = hi ? bs : a;
  unsigned nb = hi ? b  : as;
  a = na; b = nb;
#endif
}
__device__ __forceinline__ float cross_max(float x){
  unsigned a = __builtin_bit_cast(unsigned, x), b = a;
  plswap(a, b);
  return fmaxf(__builtin_bit_cast(float, a), __builtin_bit_cast(float, b));
}
__device__ __forceinline__ float cross_sum(float x){
  unsigned a = __builtin_bit_cast(unsigned, x), b = a;
  plswap(a, b);
  return __builtin_bit_cast(float, a) + __builtin_bit_cast(float, b);
}

// async global->LDS, 16B per lane; LDS dest = wave-uniform base + lane*16
__device__ __forceinline__ void gload16(const void* g, void* l){
  __builtin_amdgcn_global_load_lds(
    (const __attribute__((address_space(1))) char*)(unsigned long long)g,
    (__attribute__((address_space(3))) char*)(unsigned int)(unsigned long long)l,
    16, 0, 0);
}

// ---------------- prep: weights -> MFMA FRAGMENT order ----------------
__global__ __launch_bounds__(256) void prep_w_kernel(const float* __restrict__ Wq,
                                                     const float* __restrict__ Wk,
                                                     const float* __restrict__ Wv,
                                                     const float* __restrict__ Wo,
                                                     bf16* __restrict__ Wqf,
                                                     bf16* __restrict__ Wkf,
                                                     bf16* __restrict__ Wvf,
                                                     bf16* __restrict__ Wof){
  int t = blockIdx.x*256 + threadIdx.x;   // 16384 threads (64 blocks)
  int which = t >> 12;
  int c = t & 4095;
  int lane = c & 63;
  int lq = lane & 15, g = lane >> 4;
  us8 v;
  if (which < 3){
    int nt = c >> 9;            // 0..7
    int ks = (c >> 6) & 7;      // 0..7
    const float* src = (which==0)?Wq:((which==1)?Wk:Wv);
    bf16* dst = (which==0)?Wqf:((which==1)?Wkf:Wvf);
    #pragma unroll
    for (int j=0;j<8;j++) v[j] = f2bits(src[(size_t)(ks*32 + g*8 + j)*U_ + nt*16 + lq]);
    *reinterpret_cast<us8*>(dst + (size_t)c*8) = v;
  } else {
    int nt = c >> 8;            // 0..15
    int ks = (c >> 6) & 3;      // 0..3
    #pragma unroll
    for (int j=0;j<8;j++) v[j] = f2bits(Wo[(size_t)(ks*32 + g*8 + j)*D_ + nt*16 + lq]);
    *reinterpret_cast<us8*>(Wof + (size_t)c*8) = v;
  }
}

// ---------------- QKV projection: coalesced X staging + frag-order weights ----------------
__global__ __launch_bounds__(256) void qkv_kernel(const float* __restrict__ X,
                                                  const bf16* __restrict__ Wqf,
                                                  const bf16* __restrict__ Wkf,
                                                  const bf16* __restrict__ Wvf,
                                                  bf16* __restrict__ Q,
                                                  bf16* __restrict__ K,
                                                  bf16* __restrict__ Vt){
  __shared__ unsigned short Xls[32][264];   // pad 264: 528B rows

  const int tid  = threadIdx.x;
  const int w    = tid >> 6;
  const int lane = tid & 63;
  const int lq   = lane & 15;
  const int g    = lane >> 4;
  const int m0   = blockIdx.x*32;
  const int n0   = w*32;

  #pragma unroll
  for (int p=0; p<8; p++){
    int row = p*4 + (tid>>6);
    int col = (tid & 63)*4;
    float4v x = *reinterpret_cast<const float4v*>(X + (size_t)(m0+row)*D_ + col);
    us4 v;
    #pragma unroll
    for (int j=0;j<4;j++) v[j] = f2bits(x[j]);
    *reinterpret_cast<us4*>(&Xls[row][col]) = v;
  }
  __syncthreads();

  bf8v af[2][8];
  #pragma unroll
  for (int rt=0; rt<2; rt++)
    #pragma unroll
    for (int ks=0; ks<8; ks++)
      af[rt][ks] = *reinterpret_cast<const bf8v*>(&Xls[rt*16+lq][ks*32 + g*8]);

  #pragma unroll
  for (int which=0; which<3; which++){
    const bf16* Wf = (which==0) ? Wqf : ((which==1) ? Wkf : Wvf);
    f4v acc[2][2];
    #pragma unroll
    for (int rt=0;rt<2;rt++)
      #pragma unroll
      for (int ct=0;ct<2;ct++) acc[rt][ct] = (f4v){0.f,0.f,0.f,0.f};

    #pragma unroll
    for (int ks=0; ks<8; ks++){
      #pragma unroll
      for (int ct=0; ct<2; ct++){
        int nt = (n0>>4) + ct;
        bf8v b = *reinterpret_cast<const bf8v*>(Wf + ((size_t)((nt*8 + ks)*64 + lane) << 3));
        acc[0][ct] = MFMA16(af[0][ks], b, acc[0][ct]);
        acc[1][ct] = MFMA16(af[1][ks], b, acc[1][ct]);
      }
    }

    if (which==0){
      const float qscale = 0.12751745562008530f;      // log2(e)/sqrt(U)
      #pragma unroll
      for (int rt=0;rt<2;rt++)
        #pragma unroll
        for (int ct=0;ct<2;ct++)
          #pragma unroll
          for (int r=0;r<4;r++)
            Q[(size_t)(m0+rt*16+g*4+r)*U_ + n0+ct*16+lq] = __float2bfloat16(acc[rt][ct][r]*qscale);
    } else if (which==1){
      #pragma unroll
      for (int rt=0;rt<2;rt++)
        #pragma unroll
        for (int ct=0;ct<2;ct++)
          #pragma unroll
          for (int r=0;r<4;r++)
            K[(size_t)(m0+rt*16+g*4+r)*U_ + n0+ct*16+lq] = __float2bfloat16(acc[rt][ct][r]);
    } else {
      #pragma unroll
      for (int rt=0;rt<2;rt++)
        #pragma unroll
        for (int ct=0;ct<2;ct++)
          #pragma unroll
          for (int r=0;r<4;r++){
            int m = m0 + rt*16 + g*4 + r;
            int bb = m >> 11;              // /S_
            int ss = m & (S_-1);
            Vt[((size_t)bb*U_ + n0+ct*16+lq)*S_ + ss] = __float2bfloat16(acc[rt][ct][r]);
          }
    }
  }
}

// ---------------- flash attention: K+V LDS-staged (dbuf), subtile-pipelined, 32x32 MFMA ----------------
// (r10/r12/r14/r16 config: 41.1us measured; VGPR 140 -> 2 waves/SIMD structural wall. FINAL.)
__global__ __launch_bounds__(256) void flash_kernel(const bf16* __restrict__ Q,
                                                    const bf16* __restrict__ K,
                                                    const bf16* __restrict__ Vt,
                                                    bf16* __restrict__ Opart,
                                                    float* __restrict__ Mst,
                                                    float* __restrict__ Lst,
                                                    int nsplit){
  __shared__ bf16 Kls[2][64*128];      // 2 x 16KB
  __shared__ bf16 Vls[2][128*64];      // 2 x 16KB

  const int n    = blockIdx.x;
  const int b    = n & 7;
  const int m    = n >> 3;
  const int s    = m % nsplit;
  const int qt   = m / nsplit;
  const int w    = threadIdx.x >> 6;
  const int lane = threadIdx.x & 63;
  const int l5   = lane & 31;
  const int hi   = lane >> 5;
  const int q0   = qt*128 + w*32;

  const int NT = S_/64;                // 32 big tiles
  const int t0 = (s*NT)/nsplit;
  const int t1 = ((s+1)*NT)/nsplit;

  const bf16* Qp = Q + (size_t)(b*S_ + q0 + l5)*U_ + hi*8;
  bf8v qf[8];
  #pragma unroll
  for (int uc=0; uc<8; uc++) qf[uc] = *reinterpret_cast<const bf8v*>(Qp + uc*16);

  f16v o[4];
  #pragma unroll
  for (int uc=0; uc<4; uc++)
    #pragma unroll
    for (int r=0; r<16; r++) o[uc][r] = 0.f;

  float mrow = -1e30f, lrow = 0.f;

  const bf16* Kbase = K  + (size_t)b*S_*U_;
  const bf16* Vtb   = Vt + (size_t)b*U_*S_;     // row u, stride S_

  auto stageK = [&](int buf, int t){
    const int r0 = w*16;
    #pragma unroll
    for (int c=0; c<4; c++){
      int row  = r0 + c*4 + (lane>>4);
      int soff = ((lane&15)<<4) ^ ((row&7)<<4);
      const char* src = (const char*)(Kbase + (size_t)(t*64 + row)*U_) + soff;
      gload16(src, (void*)&Kls[buf][(r0 + c*4)*128]);
    }
  };
  auto stageV = [&](int buf, int t){
    const int r0 = w*32;
    #pragma unroll
    for (int c=0; c<4; c++){
      int u    = r0 + c*8 + (lane>>3);
      int soff = ((lane&7)<<4) ^ ((u&7)<<4);
      const char* src = (const char*)(Vtb + (size_t)u*S_ + t*64) + soff;
      gload16(src, (void*)&Vls[buf][(r0 + c*8)*64]);
    }
  };

  auto process = [&](f16v &st, const char* vb0, int sub){
    float p[16];
    #pragma unroll
    for (int r=0;r<16;r++) p[r] = st[r];

    float a0 = fmaxf(p[0],p[1]),  a1 = fmaxf(p[2],p[3]);
    float a2 = fmaxf(p[4],p[5]),  a3 = fmaxf(p[6],p[7]);
    float a4 = fmaxf(p[8],p[9]),  a5 = fmaxf(p[10],p[11]);
    float a6 = fmaxf(p[12],p[13]),a7 = fmaxf(p[14],p[15]);
    float b0 = fmaxf(a0,a1), b1 = fmaxf(a2,a3), b2 = fmaxf(a4,a5), b3 = fmaxf(a6,a7);
    float tm = fmaxf(fmaxf(b0,b1), fmaxf(b2,b3));
    tm = cross_max(tm);

    if (!__all(tm <= mrow + 11.54f)){        // defer-max (8 nats in log2)
      float mn    = fmaxf(mrow, tm);
      float alpha = EXP2(mrow - mn);
      lrow *= alpha;
      #pragma unroll
      for (int uc=0;uc<4;uc++)
        #pragma unroll
        for (int r=0;r<16;r++) o[uc][r] *= alpha;
      mrow = mn;
    }

    #pragma unroll
    for (int r=0;r<16;r++) p[r] = EXP2(p[r]-mrow);
    float s0s = (p[0]+p[1]) + (p[2]+p[3]);
    float s1s = (p[4]+p[5]) + (p[6]+p[7]);
    float s2s = (p[8]+p[9]) + (p[10]+p[11]);
    float s3s = (p[12]+p[13]) + (p[14]+p[15]);
    lrow += cross_sum((s0s+s1s) + (s2s+s3s));

    unsigned c0 = (unsigned)f2bits(p[0])  | ((unsigned)f2bits(p[1])<<16);
    unsigned c1 = (unsigned)f2bits(p[2])  | ((unsigned)f2bits(p[3])<<16);
    unsigned c2 = (unsigned)f2bits(p[4])  | ((unsigned)f2bits(p[5])<<16);
    unsigned c3 = (unsigned)f2bits(p[6])  | ((unsigned)f2bits(p[7])<<16);
    unsigned c4 = (unsigned)f2bits(p[8])  | ((unsigned)f2bits(p[9])<<16);
    unsigned c5 = (unsigned)f2bits(p[10]) | ((unsigned)f2bits(p[11])<<16);
    unsigned c6 = (unsigned)f2bits(p[12]) | ((unsigned)f2bits(p[13])<<16);
    unsigned c7 = (unsigned)f2bits(p[14]) | ((unsigned)f2bits(p[15])<<16);
    plswap(c0, c2);
    plswap(c1, c3);
    plswap(c4, c6);
    plswap(c5, c7);
    u4v w0v = {c0, c1, c2, c3};
    u4v w1v = {c4, c5, c6, c7};
    bf8v pa0 = __builtin_bit_cast(bf8v, w0v);   // P[q=l5][k = hi*8+j]
    bf8v pa1 = __builtin_bit_cast(bf8v, w1v);   // P[q=l5][k = 16+hi*8+j]

    __builtin_amdgcn_s_setprio(1);
    #pragma unroll
    for (int uc=0; uc<4; uc++){
      const char* vrow = vb0 + (uc*32 + l5)*128;
      bf8v v0 = *reinterpret_cast<const bf8v*>(vrow + ((sub*64      + hi*16) ^ ((l5&7)<<4)));
      bf8v v1 = *reinterpret_cast<const bf8v*>(vrow + ((sub*64 + 32 + hi*16) ^ ((l5&7)<<4)));
      o[uc] = MFMA32(v0, pa0, o[uc]);
      o[uc] = MFMA32(v1, pa1, o[uc]);
    }
    __builtin_amdgcn_s_setprio(0);
  };

  stageK(0, t0); stageV(0, t0);
  int cur = 0;
  for (int tt=t0; tt<t1; ++tt){
    int tn = (tt+1 < NT) ? (tt+1) : (NT-1);
    stageK(cur^1, tn); stageV(cur^1, tn);              // 8 vmem in flight for t+1
    asm volatile("s_waitcnt vmcnt(8)" ::: "memory");   // tile tt fully staged
    __builtin_amdgcn_s_barrier();
    unsigned bufoff = (unsigned)cur * 16384u;          // launder: pin LDS reads after barrier
    asm volatile("" : "+v"(bufoff) : : "memory");
    const char* kb0 = (const char*)&Kls[0][0] + bufoff;
    const char* vb0 = (const char*)&Vls[0][0] + bufoff;

    // ---- QK^T for BOTH subtiles up front ----
    f16v stA, stB;
    #pragma unroll
    for (int r=0;r<16;r++){ stA[r]=0.f; stB[r]=0.f; }
    __builtin_amdgcn_s_setprio(1);
    #pragma unroll
    for (int uc=0; uc<4; uc++){
      bf8v ka = *reinterpret_cast<const bf8v*>(kb0 + l5*256 + ((uc*64      + hi*16) ^ ((l5&7)<<4)));
      bf8v kc = *reinterpret_cast<const bf8v*>(kb0 + l5*256 + ((uc*64 + 32 + hi*16) ^ ((l5&7)<<4)));
      stA = MFMA32(ka, qf[2*uc],   stA);
      stA = MFMA32(kc, qf[2*uc+1], stA);
    }
    #pragma unroll
    for (int uc=0; uc<4; uc++){
      bf8v ka = *reinterpret_cast<const bf8v*>(kb0 + 8192 + l5*256 + ((uc*64      + hi*16) ^ ((l5&7)<<4)));
      bf8v kc = *reinterpret_cast<const bf8v*>(kb0 + 8192 + l5*256 + ((uc*64 + 32 + hi*16) ^ ((l5&7)<<4)));
      stB = MFMA32(ka, qf[2*uc],   stB);
      stB = MFMA32(kc, qf[2*uc+1], stB);
    }
    __builtin_amdgcn_s_setprio(0);

    process(stA, vb0, 0);
    process(stB, vb0, 1);

    asm volatile("" ::: "memory");
    __builtin_amdgcn_s_barrier();    // all waves done reading buffers before restage
    cur ^= 1;
  }

  // ---- epilogue: per-wave (q-rows disjoint) normalized partial + stats ----
  const size_t rowg = (size_t)(b*S_ + q0 + l5);
  if (hi==0){
    Mst[(size_t)s*BS_ + rowg] = mrow;
    Lst[(size_t)s*BS_ + rowg] = lrow;
  }
  float inv = 1.0f / lrow;
  bf16* Op = Opart + (size_t)s*BS_*U_ + rowg*U_;
  #pragma unroll
  for (int uc=0; uc<4; uc++){
    #pragma unroll
    for (int g2=0; g2<4; g2++){
      us4 outv;
      #pragma unroll
      for (int j=0;j<4;j++) outv[j] = f2bits(o[uc][g2*4+j]*inv);
      *reinterpret_cast<us4*>(Op + uc*32 + g2*8 + hi*4) = outv;
    }
  }
}

// ---------------- output projection + residual, combine fused + LDS-staged A + frag weights ----------------
template<int NS>
__global__ __launch_bounds__(256) void oproj_kernel(const bf16* __restrict__ Opart,
                                                    const float* __restrict__ Mst,
                                                    const float* __restrict__ Lst,
                                                    const bf16* __restrict__ Wof,
                                                    const float* __restrict__ X,
                                                    const float* __restrict__ bo,
                                                    float* __restrict__ Y){
  __shared__ unsigned short Als[64][136];

  const int tid  = threadIdx.x;
  const int w    = tid >> 6;
  const int lane = tid & 63;
  const int lq   = lane & 15;
  const int g    = lane >> 4;
  const int m0   = blockIdx.x*64;
  const int n0   = blockIdx.y*128;

  const unsigned short* Ou = reinterpret_cast<const unsigned short*>(Opart);
  #pragma unroll
  for (int p=0; p<4; p++){
    int rl  = p*16 + (tid>>4);
    int c8  = (tid & 15)*8;
    int row = m0 + rl;
    float cw[NS];
    float M = -1e30f;
    #pragma unroll
    for (int s=0;s<NS;s++){ cw[s] = Mst[(size_t)s*BS_ + row]; M = fmaxf(M, cw[s]); }
    float L = 0.f;
    #pragma unroll
    for (int s=0;s<NS;s++){ cw[s] = Lst[(size_t)s*BS_ + row]*EXP2(cw[s]-M); L += cw[s]; }
    float inv = 1.0f / L;
    float av[8];
    #pragma unroll
    for (int j=0;j<8;j++) av[j] = 0.f;
    #pragma unroll
    for (int s=0;s<NS;s++){
      us8 pp = *reinterpret_cast<const us8*>(Ou + (size_t)s*BS_*U_ + (size_t)row*U_ + c8);
      #pragma unroll
      for (int j=0;j<8;j++) av[j] += cw[s]*b2f(pp[j]);
    }
    us8 aw;
    #pragma unroll
    for (int j=0;j<8;j++) aw[j] = f2bits(av[j]*inv);
    *reinterpret_cast<us8*>(&Als[rl][c8]) = aw;
  }
  __syncthreads();

  f4v acc[8];
  #pragma unroll
  for (int i=0;i<8;i++) acc[i] = (f4v){0.f,0.f,0.f,0.f};

  #pragma unroll
  for (int ks=0; ks<4; ks++){
    bf8v a = *reinterpret_cast<const bf8v*>(&Als[w*16+lq][ks*32 + g*8]);
    #pragma unroll
    for (int nc=0;nc<8;nc++){
      int nt = (n0>>4) + nc;
      bf8v bb = *reinterpret_cast<const bf8v*>(Wof + ((size_t)((nt*4 + ks)*64 + lane) << 3));
      acc[nc] = MFMA16(a, bb, acc[nc]);
    }
  }

  #pragma unroll
  for (int nc=0;nc<8;nc++){
    int col = n0 + nc*16 + lq;
    float bias = bo[col];
    #pragma unroll
    for (int r=0;r<4;r++){
      int orow = m0 + w*16 + g*4 + r;
      Y[(size_t)orow*D_ + col] = acc[nc][r] + bias + X[(size_t)orow*D_ + col];
    }
  }
}

extern "C" void kernel_launch(void* const* d_in, const int* in_sizes, int n_in,
                              void* d_out, int out_size, void* d_ws, size_t ws_size,
                              hipStream_t stream) {
  (void)in_sizes; (void)n_in; (void)out_size;
  const float* X  = (const float*)d_in[0];
  const float* Wq = (const float*)d_in[1];
  const float* Wk = (const float*)d_in[2];
  const float* Wv = (const float*)d_in[3];
  const float* Wo = (const float*)d_in[4];
  const float* bo = (const float*)d_in[5];
  float* Y = (float*)d_out;

  const size_t MB = 1u<<20;
  int nsplit = (ws_size >= 30408704u) ? 4 : 2;   // ns=4 footprint ~29.1MB

  char* ws = (char*)d_ws;
  bf16* Opart = (bf16*)ws;
  size_t off = (size_t)nsplit*4*MB;
  bf16* Qb  = (bf16*)(ws + off); off += 4*MB;
  bf16* Kb  = (bf16*)(ws + off); off += 4*MB;
  bf16* Vtb = (bf16*)(ws + off); off += 4*MB;
  bf16* Wqf = (bf16*)(ws + off); off += 65536;
  bf16* Wkf = (bf16*)(ws + off); off += 65536;
  bf16* Wvf = (bf16*)(ws + off); off += 65536;
  bf16* Wof = (bf16*)(ws + off); off += 65536;
  float* Mst = (float*)(ws + off); off += (size_t)nsplit*BS_*4;
  float* Lst = (float*)(ws + off);

  prep_w_kernel<<<dim3(64), dim3(256), 0, stream>>>(Wq, Wk, Wv, Wo, Wqf, Wkf, Wvf, Wof);
  qkv_kernel<<<dim3(BS_/32), dim3(256), 0, stream>>>(X, Wqf, Wkf, Wvf, Qb, Kb, Vtb);
  flash_kernel<<<dim3(16*nsplit*8), dim3(256), 0, stream>>>(Qb, Kb, Vtb, Opart, Mst, Lst, nsplit);
  if (nsplit == 4){
    oproj_kernel<4><<<dim3(BS_/64, 2), dim3(256), 0, stream>>>(Opart, Mst, Lst, Wof, X, bo, Y);
  } else {
    oproj_kernel<2><<<dim3(BS_/64, 2), dim3(256), 0, stream>>>(Opart, Mst, Lst, Wof, X, bo, Y);
  }
}